// Round 6
// baseline (2664.965 us; speedup 1.0000x reference)
//
#include <hip/hip_runtime.h>
#include <math.h>

#define NB 8
#define NC 684
#define NH 16
#define NW 64
#define NHW 1024
#define NHID 256
#define NAD 512
#define NV 111
#define NT 36

__device__ __forceinline__ float wred_sum(float v){
  #pragma unroll
  for (int o = 32; o > 0; o >>= 1) v += __shfl_xor(v, o, 64);
  return v;
}
__device__ __forceinline__ float wred_max(float v){
  #pragma unroll
  for (int o = 32; o > 0; o >>= 1) v = fmaxf(v, __shfl_xor(v, o, 64));
  return v;
}
__device__ __forceinline__ float fsig(float x){ return 1.f/(1.f + __expf(-x)); }
__device__ __forceinline__ float ftanh(float x){ float e = __expf(2.f*x); return 1.f - 2.f/(e + 1.f); }

// ---------------- P0: dmask, msum, ys/xs, idt, zero abuf[0] (=A(0))
__global__ void k_p0(const float* __restrict__ im, float* __restrict__ dmask,
                     float* __restrict__ msum, float* __restrict__ ys, float* __restrict__ xs,
                     float* __restrict__ idt, float* __restrict__ abuf)
{
  const int tid = threadIdx.x; // 256 threads, 1 block
  for (int i = tid; i < NB*NHW; i += 256){
    int b = i >> 10, hw = i & 1023; int h = hw >> 6, w = hw & 63;
    dmask[i] = im[b*(256*1024) + (h*16)*1024 + (w*16)];
    abuf[i] = 0.f;
  }
  if (tid < 128) idt[tid] = expf(-(float)tid * (9.210340371976184f/128.f));
  __syncthreads();
  if (tid < 8){
    float s = 0.f;
    for (int i = 0; i < NHW; i++) s += dmask[tid*NHW + i];
    msum[tid] = s;
  }
  for (int p = tid; p < NB*NW; p += 256){
    int b = p >> 6, w = p & 63;
    float tot = 0.f;
    for (int h = 0; h < NH; h++) tot += dmask[b*NHW + h*64 + w];
    float inv = 6.283185307179586f/(tot + 1e-6f);
    float run = 0.f;
    for (int h = 0; h < NH; h++){ run += dmask[b*NHW + h*64 + w]; ys[b*NHW + h*64 + w] = run*inv; }
  }
  for (int p = tid; p < NB*NH; p += 256){
    int b = p >> 4, h = p & 15;
    float tot = 0.f;
    for (int w = 0; w < NW; w++) tot += dmask[b*NHW + h*64 + w];
    float inv = 6.283185307179586f/(tot + 1e-6f);
    float run = 0.f;
    for (int w = 0; w < NW; w++){ run += dmask[b*NHW + h*64 + w]; xs[b*NHW + h*64 + w] = run*inv; }
  }
}

// ---------------- P1: masked average
__global__ void k_avg(const float* __restrict__ cnn, const float* __restrict__ dmask,
                      const float* __restrict__ msum, float* __restrict__ avg)
{
  int gid = blockIdx.x*blockDim.x + threadIdx.x;
  int gw = gid >> 6, lane = gid & 63;
  int nw = (gridDim.x*blockDim.x) >> 6;
  for (int ow = gw; ow < NB*NC; ow += nw){
    int b = ow / NC;
    const float* base = cnn + (size_t)ow * NHW;
    const float* dm = dmask + b*NHW;
    float s = 0.f;
    for (int i = lane; i < NHW; i += 64) s += base[i]*dm[i];
    s = wred_sum(s);
    if (lane == 0) avg[ow] = s / msum[b];
  }
}

// ---------------- P2: hidden(-1) (into hbuf[1]) + counting_ctx
__global__ void k_init(const float* __restrict__ avg, const float* __restrict__ iW, const float* __restrict__ ib,
                       const float* __restrict__ cp, const float* __restrict__ cW, const float* __restrict__ cb,
                       float* __restrict__ hid, float* __restrict__ cctx)
{
  int gid = blockIdx.x*blockDim.x + threadIdx.x;
  int gw = gid >> 6, lane = gid & 63;
  int nw = (gridDim.x*blockDim.x) >> 6;
  for (int ow = gw; ow < 2*NB*NHID; ow += nw){
    if (ow < NB*NHID){
      int b = ow >> 8, j = ow & 255;
      float s = 0.f;
      for (int k = lane; k < NC; k += 64) s += avg[b*NC + k]*iW[j*NC + k];
      s = wred_sum(s);
      if (lane == 0) hid[ow] = tanhf(s + ib[j]);
    } else {
      int o = ow - NB*NHID; int b = o >> 8, j = o & 255;
      float s = 0.f;
      for (int k = lane; k < NV; k += 64) s += cp[b*NV + k]*cW[j*NV + k];
      s = wred_sum(s);
      if (lane == 0) cctx[o] = s + cb[j];
    }
  }
}

// ---------------- P3: trans GEMM (128x64 tile, 8x4/thread) + bias + sine pos-emb
__global__ __launch_bounds__(256) void k_trans(const float* __restrict__ cnn, const float* __restrict__ ew,
     const float* __restrict__ eb, const float* __restrict__ ys, const float* __restrict__ xs,
     const float* __restrict__ idt, float* __restrict__ trans)
{
  const int m0 = blockIdx.x << 7;   // hw-major, 64 tiles
  const int n0 = blockIdx.y << 6;   // 8 d-tiles
  const int b  = m0 >> 10;
  const int hw0 = m0 & 1023;
  __shared__ float As[16][132];
  __shared__ float Bs[16][68];
  const int tid = threadIdx.x;
  const int tx = tid & 15, ty = tid >> 4;   // tx -> n (4 each), ty -> m (8 each)
  float acc[8][4];
  #pragma unroll
  for (int i=0;i<8;i++)
    #pragma unroll
    for (int j=0;j<4;j++) acc[i][j]=0.f;
  for (int c0 = 0; c0 < NC; c0 += 16){
    #pragma unroll
    for (int u = 0; u < 8; u++){
      int idx = tid + (u<<8);
      int cc = idx >> 7, mm = idx & 127;
      int c = c0 + cc;
      As[cc][mm] = (c < NC) ? cnn[((size_t)b*NC + c)*NHW + hw0 + mm] : 0.f;
    }
    #pragma unroll
    for (int u = 0; u < 4; u++){
      int idx = tid + (u<<8);
      int nn = idx >> 4, cc = idx & 15;
      int c = c0 + cc;
      Bs[cc][nn] = (c < NC) ? ew[(size_t)(n0 + nn)*NC + c] : 0.f;
    }
    __syncthreads();
    #pragma unroll
    for (int k = 0; k < 16; k++){
      float4 a0 = *(const float4*)&As[k][ty*8];
      float4 a1 = *(const float4*)&As[k][ty*8+4];
      float4 bb = *(const float4*)&Bs[k][tx*4];
      float a[8] = {a0.x,a0.y,a0.z,a0.w,a1.x,a1.y,a1.z,a1.w};
      #pragma unroll
      for (int i=0;i<8;i++){
        acc[i][0] += a[i]*bb.x; acc[i][1] += a[i]*bb.y;
        acc[i][2] += a[i]*bb.z; acc[i][3] += a[i]*bb.w;
      }
    }
    __syncthreads();
  }
  const int dbase = n0 + tx*4;
  float ebv[4], idtv[4]; int codd[4];
  #pragma unroll
  for (int j = 0; j < 4; j++){
    int d = dbase + j;
    ebv[j] = eb[d];
    idtv[j] = (d < 256) ? idt[d>>1] : idt[(d-256)>>1];
    codd[j] = d & 1;
  }
  const int usex = dbase >= 256;
  #pragma unroll
  for (int i = 0; i < 8; i++){
    int hw = hw0 + ty*8 + i;
    float base = usex ? xs[(b<<10) + hw] : ys[(b<<10) + hw];
    float o[4];
    #pragma unroll
    for (int j = 0; j < 4; j++){
      float arg = base*idtv[j];
      float pe = codd[j] ? cosf(arg) : sinf(arg);
      o[j] = acc[i][j] + ebv[j] + pe;
    }
    *(float4*)(trans + ((size_t)(b<<10) + hw)*NAD + dbase) = make_float4(o[0],o[1],o[2],o[3]);
  }
}

// ---------------- P4: gi + embw for all steps
__global__ void k_pre(const int* __restrict__ labels, const float* __restrict__ emb,
    const float* __restrict__ wih, const float* __restrict__ bih,
    const float* __restrict__ ewW, const float* __restrict__ ewb,
    float* __restrict__ gi, float* __restrict__ embw)
{
  int gid = blockIdx.x*blockDim.x + threadIdx.x;
  int gw = gid >> 6, lane = gid & 63;
  int nw = (gridDim.x*blockDim.x) >> 6;
  const int NGI = NT*NB*768;
  const int NEW_ = NT*NB*256;
  for (int ow = gw; ow < NGI + NEW_; ow += nw){
    if (ow < NGI){
      int i = ow % 768; int tb = ow / 768; int b = tb & 7, t = tb >> 3;
      int word = (t == 0) ? 1 : labels[b*NT + t - 1];
      const float* er = emb + (size_t)word*256;
      float s = 0.f;
      for (int k = lane; k < 256; k += 64) s += er[k]*wih[(size_t)i*256 + k];
      s = wred_sum(s);
      if (lane == 0) gi[ow] = s + bih[i];
    } else {
      int o = ow - NGI; int j = o & 255; int tb = o >> 8; int b = tb & 7, t = tb >> 3;
      int word = (t == 0) ? 1 : labels[b*NT + t - 1];
      const float* er = emb + (size_t)word*256;
      float s = 0.f;
      for (int k = lane; k < 256; k += 64) s += er[k]*ewW[(size_t)j*256 + k];
      s = wred_sum(s);
      if (lane == 0) embw[o] = s + ewb[j];
    }
  }
}

// ---------------- P5: Mt[tap][d] = sum_c att_weight_W[d,c]*att_conv_w[c,0,tap]
__global__ void k_mt(const float* __restrict__ aw, const float* __restrict__ acw, float* __restrict__ Mt)
{
  __shared__ float col[512];
  int t = blockIdx.x; int tid = threadIdx.x;  // 121 x 256
  for (int c = tid; c < 512; c += 256) col[c] = acw[(size_t)c*121 + t];
  __syncthreads();
  for (int d = tid; d < 512; d += 256){
    float s = 0.f;
    const float4* r4 = (const float4*)(aw + (size_t)d*512);
    for (int k = 0; k < 128; k++){
      float4 w = r4[k];
      s += col[k*4+0]*w.x + col[k*4+1]*w.y + col[k*4+2]*w.z + col[k*4+3]*w.w;
    }
    Mt[t*512 + d] = s;
  }
}

// ---------------- P6: SO = oW@sW; CB[b][v] = ob[v] + (sb+cxb+cctx[b])·oW[v]
__global__ __launch_bounds__(256) void k_so(const float* __restrict__ sW, const float* __restrict__ oW,
    const float* __restrict__ sb, const float* __restrict__ cxb, const float* __restrict__ cctx,
    const float* __restrict__ ob, float* __restrict__ SO, float* __restrict__ CB)
{
  const int v = blockIdx.x; const int tid = threadIdx.x;
  float acc = 0.f;
  for (int j = 0; j < 256; j++) acc += sW[(size_t)j*256 + tid] * oW[(size_t)v*256 + j];
  SO[(size_t)v*256 + tid] = acc;
  if (tid < 8){
    float s = ob[v];
    for (int j = 0; j < 256; j++) s += (sb[j] + cxb[j] + cctx[tid*256 + j]) * oW[(size_t)v*256 + j];
    CB[tid*NV + v] = s;
  }
}

// ---------------- P7: embwO[t*8+b][v] = embw[t*8+b]·oW[v]
__global__ __launch_bounds__(512) void k_embwO(const float* __restrict__ embw, const float* __restrict__ oW,
                                               float* __restrict__ embwO)
{
  const int v = blockIdx.x; const int tid = threadIdx.x;
  const int lane = tid & 63, wid = tid >> 6;
  __shared__ float ows[256];
  if (tid < 256) ows[tid] = oW[(size_t)v*256 + tid];
  __syncthreads();
  for (int tb = wid; tb < NT*NB; tb += 8){
    float acc = 0.f;
    #pragma unroll
    for (int u = 0; u < 4; u++){ int j = lane + (u<<6); acc += embw[(size_t)tb*256 + j]*ows[j]; }
    acc = wred_sum(acc);
    if (lane == 0) embwO[tb*NV + v] = acc;
  }
}

// ---------------- P8: CO[c][v] = sum_j cxW[j,c]*oW[v,j] (padded [c][128])
__global__ __launch_bounds__(256) void k_co(const float* __restrict__ cxW, const float* __restrict__ oW,
                                            float* __restrict__ CO)
{
  const int c = blockIdx.x*256 + threadIdx.x;
  const int v = blockIdx.y;
  if (c >= NC) return;
  float acc = 0.f;
  for (int j = 0; j < 256; j++) acc += cxW[(size_t)j*NC + c] * oW[(size_t)v*256 + j];
  CO[(size_t)c*128 + v] = acc;
  if (v == 0){
    for (int vv = NV; vv < 128; vv++) CO[(size_t)c*128 + vv] = 0.f;
  }
}

// ---------------- P9: PO[b][v][hw] = sum_c cnn[b,c,hw]*CO[c][v] (64x64 tile, 4x4/thread)
__global__ __launch_bounds__(256) void k_gemm_PO(const float* __restrict__ cnn, const float* __restrict__ CO,
                                                 float* __restrict__ PO)
{
  const int m0 = blockIdx.x << 6;   // hw
  const int n0 = blockIdx.y << 6;   // v
  const int b  = blockIdx.z;
  __shared__ float As[32][64];
  __shared__ float Bs[32][65];
  const int tid = threadIdx.x;
  const int tx = tid & 15, ty = tid >> 4;  // tx -> m(hw), ty -> n(v)
  float acc[4][4];  // [m][n]
  #pragma unroll
  for (int i=0;i<4;i++)
    #pragma unroll
    for (int j=0;j<4;j++) acc[i][j]=0.f;
  for (int c0 = 0; c0 < NC; c0 += 32){
    int kc = NC - c0; if (kc > 32) kc = 32;
    for (int idx = tid; idx < 32*64; idx += 256){
      int cc = idx >> 6, mm = idx & 63;
      As[cc][mm] = (cc < kc) ? cnn[((size_t)b*NC + c0 + cc)*NHW + m0 + mm] : 0.f;
    }
    for (int idx = tid; idx < 32*64; idx += 256){
      int cc = idx >> 6, nn = idx & 63;
      Bs[cc][nn] = (cc < kc) ? CO[(size_t)(c0 + cc)*128 + n0 + nn] : 0.f;
    }
    __syncthreads();
    #pragma unroll
    for (int k = 0; k < 32; k++){
      float a0 = As[k][tx*4+0], a1 = As[k][tx*4+1], a2 = As[k][tx*4+2], a3 = As[k][tx*4+3];
      float b0 = Bs[k][ty*4+0], b1 = Bs[k][ty*4+1], b2 = Bs[k][ty*4+2], b3 = Bs[k][ty*4+3];
      acc[0][0]+=a0*b0; acc[0][1]+=a0*b1; acc[0][2]+=a0*b2; acc[0][3]+=a0*b3;
      acc[1][0]+=a1*b0; acc[1][1]+=a1*b1; acc[1][2]+=a1*b2; acc[1][3]+=a1*b3;
      acc[2][0]+=a2*b0; acc[2][1]+=a2*b1; acc[2][2]+=a2*b2; acc[2][3]+=a2*b3;
      acc[3][0]+=a3*b0; acc[3][1]+=a3*b1; acc[3][2]+=a3*b2; acc[3][3]+=a3*b3;
    }
    __syncthreads();
  }
  #pragma unroll
  for (int j = 0; j < 4; j++){
    int v = n0 + ty*4 + j;
    float* dst = PO + (((size_t)b*128 + v)<<10) + m0 + tx*4;
    *(float4*)dst = make_float4(acc[0][j],acc[1][j],acc[2][j],acc[3][j]);
  }
}

// ---------------- gru slice helper (64 j per r) — prologue only
__device__ __forceinline__ void gru_slice(const float* __restrict__ hs, const float* __restrict__ whh,
    const float* __restrict__ bhh, const float* __restrict__ gg, float* __restrict__ hdst,
    int r, int wid, int lane)
{
  #pragma unroll 1
  for (int jj = 0; jj < 8; jj++){
    int j = (r<<6) + (wid<<3) + jj;
    float sr = 0.f, sz = 0.f, sn = 0.f;
    #pragma unroll
    for (int u = 0; u < 4; u++){
      int k = lane + (u<<6);
      float hv = hs[k];
      sr += hv * whh[(size_t)j*256 + k];
      sz += hv * whh[(size_t)(j+256)*256 + k];
      sn += hv * whh[(size_t)(j+512)*256 + k];
    }
    sr = wred_sum(sr); sz = wred_sum(sz); sn = wred_sum(sn);
    if (lane == 0){
      float rr = 1.f/(1.f + expf(-(gg[j] + sr + bhh[j])));
      float zz = 1.f/(1.f + expf(-(gg[j+256] + sz + bhh[j+256])));
      float nn = tanhf(gg[j+512] + rr*(sn + bhh[j+512]));
      hdst[j] = (1.f - zz)*nn + zz*hs[j];
    }
  }
}

// ---------------- P10: initial GRU (t=0): hbuf[1] -> hbuf[0]
__global__ __launch_bounds__(512) void k_gq0(const float* __restrict__ hbuf1, const float* __restrict__ whh,
    const float* __restrict__ bhh, const float* __restrict__ gi, float* __restrict__ hbuf0)
{
  const int r = blockIdx.x, b = blockIdx.y;
  const int tid = threadIdx.x, lane = tid & 63, wid = tid >> 6;
  __shared__ float hs[256];
  if (tid < 256) hs[tid] = hbuf1[(b<<8) + tid];
  __syncthreads();
  gru_slice(hs, whh, bhh, gi + (size_t)b*768, hbuf0 + (b<<8), r, wid, lane);
}

// ---------------- P11: query(0) into qbuf[0]
__global__ __launch_bounds__(512) void k_query0(const float* __restrict__ hbuf, const float* __restrict__ ahW,
    const float* __restrict__ ahb, float* __restrict__ qbuf)
{
  const int b = blockIdx.x >> 3, dc = blockIdx.x & 7;
  const int tid = threadIdx.x, lane = tid & 63, wid = tid >> 6;
  __shared__ float hs[256];
  if (tid < 256) hs[tid] = hbuf[(b<<8) + tid];
  __syncthreads();
  #pragma unroll 1
  for (int i = 0; i < 8; i++){
    int d = (dc<<6) + (wid<<3) + i;
    float acc = 0.f;
    #pragma unroll
    for (int u = 0; u < 4; u++){ int k = lane + (u<<6); acc += hs[k]*ahW[(size_t)d*256 + k]; }
    acc = wred_sum(acc);
    if (lane == 0) qbuf[(b<<9) + d] = acc + ahb[d];
  }
}

// ---------------- P12: weight transposes (whhT [g][k][j], ahWT [k][d])
__global__ void k_tr(const float* __restrict__ whh, const float* __restrict__ ahW,
                     float* __restrict__ whhT, float* __restrict__ ahWT)
{
  int i = blockIdx.x*256 + threadIdx.x;
  int stride = gridDim.x*256;
  for (int x = i; x < 768*256; x += stride){
    int g = x >> 16, k = (x >> 8) & 255, j = x & 255;
    whhT[x] = whh[(size_t)((g<<8)+j)*256 + k];
  }
  for (int x = i; x < 256*512; x += stride){
    int k = x >> 9, d = x & 511;
    ahWT[x] = ahW[(size_t)(d<<8) + k];
  }
}

// ================= per-step single kernel =================
// blocks 0..255: softmax(t-1) locally -> energy(t)   [wave owns 4 w, lane owns 8 d]
// blocks 256..263: softmax(t-1) -> asum write + prob(t-1); gru+query(t+1)
// double buffers: ebuf[t&1]=energy(t), abuf[t&1]=A(t)=sum_{s<t} alpha(s); hbuf[t&1]=h(t); qbuf[t&1]=q(t)
__global__ __launch_bounds__(512) void k_step(
  const float* __restrict__ dmask, const float* __restrict__ Mt,
  const float* __restrict__ trans, float* __restrict__ qbuf,
  const float* __restrict__ acvW, const float* __restrict__ acvb,
  const float* __restrict__ PO, const float* __restrict__ SO,
  const float* __restrict__ CB, const float* __restrict__ embwO,
  const float* __restrict__ gi, const float* __restrict__ whhT,
  const float* __restrict__ bhh, const float* __restrict__ ahWT,
  const float* __restrict__ ahb, float* __restrict__ hbuf,
  float* __restrict__ abuf, float* __restrict__ ebuf,
  float* __restrict__ out, int t)
{
  const int gid = blockIdx.x, tid = threadIdx.x;
  const int lane = tid & 63, wv = tid >> 6;
  __shared__ float al[1024];
  __shared__ float as[11][42];
  __shared__ float hs[256], hn[256];
  __shared__ float red[18];

  const float* eprev = ebuf + (((t+1)&1)<<13);
  float*       ecur  = ebuf + ((t&1)<<13);
  const float* aprev = abuf + (((t+1)&1)<<13);
  float*       acur  = abuf + ((t&1)<<13);

  if (gid < 256){
    if (t >= NT) return;
    const int whalf = gid & 1, h = (gid>>1)&15, b = gid>>5;
    const int w0 = whalf<<5;
    // ---- local softmax of step t-1 into al[]
    if (t > 0){
      float e0 = eprev[(b<<10)+tid], e1 = eprev[(b<<10)+512+tid];
      float dm0 = dmask[(b<<10)+tid], dm1 = dmask[(b<<10)+512+tid];
      float m = wred_max(fmaxf(e0, e1));
      if (lane == 0) red[wv] = m;
      __syncthreads();
      if (tid == 0){
        float g = red[0];
        #pragma unroll
        for (int i = 1; i < 8; i++) g = fmaxf(g, red[i]);
        red[16] = g;
      }
      __syncthreads();
      float g = red[16];
      float x0 = __expf(e0 - g)*dm0, x1 = __expf(e1 - g)*dm1;
      float s = wred_sum(x0 + x1);
      if (lane == 0) red[wv] = s;
      __syncthreads();
      if (tid == 0){
        float ss = 0.f;
        #pragma unroll
        for (int i = 0; i < 8; i++) ss += red[i];
        red[17] = ss;
      }
      __syncthreads();
      float inv = 1.f/(red[17] + 1e-10f);
      al[tid] = x0*inv; al[512+tid] = x1*inv;
    }
    __syncthreads();
    // ---- halo: as = A(t-1) + alpha(t-1)
    for (int idx = tid; idx < 462; idx += 512){
      int r = idx/42, c = idx - r*42;
      int hi = h + r - 5, wi = w0 + c - 5;
      float v = 0.f;
      if (t > 0 && (unsigned)hi < 16u && (unsigned)wi < 64u){
        int p = (hi<<6) + wi;
        v = aprev[(b<<10)+p] + al[p];
      }
      as[r][c] = v;
    }
    __syncthreads();
    // ---- stencil: wave wv owns w = w0+wv*4..+3, lane owns d = lane*8..+7
    const int woff = wv<<2, d0 = lane<<3;
    float acc[4][8];
    #pragma unroll
    for (int i=0;i<4;i++)
      #pragma unroll
      for (int j=0;j<8;j++) acc[i][j]=0.f;
    #pragma unroll 1
    for (int ki = 0; ki < 11; ki++){
      float row[14];
      #pragma unroll
      for (int j = 0; j < 14; j++) row[j] = as[ki][woff + j];
      float mx = 0.f;
      #pragma unroll
      for (int j = 0; j < 14; j++) mx = fmaxf(mx, fabsf(row[j]));
      if (mx != 0.f){
        const float* mtp = Mt + (ki*11)*512 + d0;
        #pragma unroll
        for (int kj = 0; kj < 11; kj++){
          float4 m0 = *(const float4*)(mtp + kj*512);
          float4 m1 = *(const float4*)(mtp + kj*512 + 4);
          #pragma unroll
          for (int wq = 0; wq < 4; wq++){
            float rv = row[wq + kj];
            acc[wq][0] += rv*m0.x; acc[wq][1] += rv*m0.y; acc[wq][2] += rv*m0.z; acc[wq][3] += rv*m0.w;
            acc[wq][4] += rv*m1.x; acc[wq][5] += rv*m1.y; acc[wq][6] += rv*m1.z; acc[wq][7] += rv*m1.w;
          }
        }
      }
    }
    // ---- tail: tanh + per-wave full reduction (each wave covers all 512 d)
    const float* qb = qbuf + ((t&1)<<12) + (b<<9) + d0;
    float4 q0 = *(const float4*)qb, q1 = *(const float4*)(qb+4);
    float4 v0 = *(const float4*)(acvW + d0), v1 = *(const float4*)(acvW + d0 + 4);
    float q8[8] = {q0.x,q0.y,q0.z,q0.w,q1.x,q1.y,q1.z,q1.w};
    float w8[8] = {v0.x,v0.y,v0.z,v0.w,v1.x,v1.y,v1.z,v1.w};
    const float acb0 = acvb[0];
    #pragma unroll
    for (int wq = 0; wq < 4; wq++){
      int hw = (h<<6) + w0 + woff + wq;
      const float* tp = trans + (((size_t)(b<<10) + hw))*NAD + d0;
      float4 t0 = *(const float4*)tp, t1 = *(const float4*)(tp+4);
      float tv[8] = {t0.x,t0.y,t0.z,t0.w,t1.x,t1.y,t1.z,t1.w};
      float sum = 0.f;
      #pragma unroll
      for (int dk = 0; dk < 8; dk++) sum += w8[dk]*ftanh(q8[dk] + tv[dk] + acc[wq][dk]);
      sum = wred_sum(sum);
      if (lane == 0) ecur[(b<<10) + hw] = sum + acb0;
    }
  } else {
    // ---- aux block for batch b
    const int b = gid - 256;
    if (t >= 1){
      float e0 = eprev[(b<<10)+tid], e1 = eprev[(b<<10)+512+tid];
      float dm0 = dmask[(b<<10)+tid], dm1 = dmask[(b<<10)+512+tid];
      float m = wred_max(fmaxf(e0, e1));
      if (lane == 0) red[wv] = m;
      __syncthreads();
      if (tid == 0){
        float g = red[0];
        #pragma unroll
        for (int i = 1; i < 8; i++) g = fmaxf(g, red[i]);
        red[16] = g;
      }
      __syncthreads();
      float g = red[16];
      float x0 = __expf(e0 - g)*dm0, x1 = __expf(e1 - g)*dm1;
      float s = wred_sum(x0 + x1);
      if (lane == 0) red[wv] = s;
      __syncthreads();
      if (tid == 0){
        float ss = 0.f;
        #pragma unroll
        for (int i = 0; i < 8; i++) ss += red[i];
        red[17] = ss;
      }
      __syncthreads();
      float inv = 1.f/(red[17] + 1e-10f);
      float a0 = x0*inv, a1 = x1*inv;
      al[tid] = a0; al[512+tid] = a1;
      acur[(b<<10)+tid]     = aprev[(b<<10)+tid]     + a0;
      acur[(b<<10)+512+tid] = aprev[(b<<10)+512+tid] + a1;
      if (tid < 256) hs[tid] = hbuf[(((t+1)&1)<<11) + (b<<8) + tid];   // h(t-1)
      __syncthreads();
      // prob(t-1)
      #pragma unroll 1
      for (int v = wv; v < NV; v += 8){
        const float* POr = PO + (((size_t)b*128 + v)<<10);
        float acc2 = 0.f;
        #pragma unroll
        for (int i = 0; i < 16; i++){ int p = lane + (i<<6); acc2 += al[p]*POr[p]; }
        const float* SOr = SO + (size_t)v*256;
        #pragma unroll
        for (int u = 0; u < 4; u++){ int k = lane + (u<<6); acc2 += hs[k]*SOr[k]; }
        acc2 = wred_sum(acc2);
        if (lane == 0)
          out[((size_t)b*NT + (t-1))*NV + v] = acc2 + CB[b*NV + v] + embwO[(((t-1)<<3)+b)*NV + v];
      }
    }
    if (t < NT-1){
      __syncthreads();
      if (tid < 256) hs[tid] = hbuf[((t&1)<<11) + (b<<8) + tid];   // h(t)
      __syncthreads();
      if (tid < 256){
        const int j = tid;
        float sr = 0.f, sz = 0.f, sn = 0.f;
        #pragma unroll 4
        for (int k = 0; k < 256; k++){
          float hv = hs[k];
          sr += hv * whhT[(k<<8) + j];
          sz += hv * whhT[((256+k)<<8) + j];
          sn += hv * whhT[((512+k)<<8) + j];
        }
        const float* gg = gi + (size_t)(((t+1)<<3) + b)*768;
        float r = fsig(gg[j] + sr + bhh[j]);
        float z = fsig(gg[j+256] + sz + bhh[j+256]);
        float n = ftanh(gg[j+512] + r*(sn + bhh[j+512]));
        float hv2 = (1.f - z)*n + z*hs[j];
        hn[j] = hv2;
        hbuf[(((t+1)&1)<<11) + (b<<8) + j] = hv2;
      }
      __syncthreads();
      {
        const int d = tid;
        float s2 = 0.f;
        #pragma unroll 4
        for (int k = 0; k < 256; k++) s2 += hn[k]*ahWT[(k<<9) + d];
        qbuf[(((t+1)&1)<<12) + (b<<9) + d] = s2 + ahb[d];
      }
    }
  }
}

extern "C" void kernel_launch(void* const* d_in, const int* in_sizes, int n_in,
                              void* d_out, int out_size, void* d_ws, size_t ws_size,
                              hipStream_t stream)
{
  const float* cnn  = (const float*)d_in[0];
  const float* cp   = (const float*)d_in[1];
  const float* im   = (const float*)d_in[2];
  const float* iW   = (const float*)d_in[3];
  const float* ib   = (const float*)d_in[4];
  const float* emb  = (const float*)d_in[5];
  const float* wih  = (const float*)d_in[6];
  const float* whh  = (const float*)d_in[7];
  const float* bih  = (const float*)d_in[8];
  const float* bhh  = (const float*)d_in[9];
  const float* ahW  = (const float*)d_in[10];
  const float* ahb  = (const float*)d_in[11];
  const float* acw  = (const float*)d_in[12];
  const float* awW  = (const float*)d_in[13];
  const float* acvW = (const float*)d_in[14];
  const float* acvb = (const float*)d_in[15];
  const float* ecw  = (const float*)d_in[16];
  const float* ecb  = (const float*)d_in[17];
  const float* sW   = (const float*)d_in[18];
  const float* sb   = (const float*)d_in[19];
  const float* ewW  = (const float*)d_in[20];
  const float* ewb  = (const float*)d_in[21];
  const float* cxW  = (const float*)d_in[22];
  const float* cxb  = (const float*)d_in[23];
  const float* cW   = (const float*)d_in[24];
  const float* cb   = (const float*)d_in[25];
  const float* oW   = (const float*)d_in[26];
  const float* ob   = (const float*)d_in[27];
  const int*   lab  = (const int*)d_in[28];
  float* out = (float*)d_out;
  float* ws = (float*)d_ws;

  float* dmask  = ws + 0;        // 8192
  float* ys     = ws + 8192;     // 8192
  float* xs     = ws + 16384;    // 8192
  float* idt    = ws + 24576;    // 128
  float* msum   = ws + 24704;    // 16
  float* avg    = ws + 24720;    // 5472
  float* cctx   = ws + 30192;    // 2048
  float* hbuf   = ws + 32240;    // 4096  (2 x 8 x 256)
  float* qbuf   = ws + 36336;    // 8192  (2 x 8 x 512)
  float* abuf   = ws + 44528;    // 16384 (2 x 8 x 1024)
  float* ebuf   = ws + 60912;    // 16384
  float* gi     = ws + 77296;    // 221184
  float* embw   = ws + 298480;   // 73728
  float* Mt     = ws + 372208;   // 61952
  float* SO     = ws + 434160;   // 28416
  float* CB     = ws + 462576;   // 896
  float* embwO  = ws + 463472;   // 32000
  float* CO     = ws + 495472;   // 87552
  float* whhT   = ws + 583024;   // 196608
  float* ahWT   = ws + 779632;   // 131072
  float* trans  = ws + 910704;   // 4194304
  float* PO     = ws + 5105008;  // 4194304   (total ~37.2 MB)

  k_p0<<<1, 256, 0, stream>>>(im, dmask, msum, ys, xs, idt, abuf);
  k_avg<<<456, 256, 0, stream>>>(cnn, dmask, msum, avg);
  k_init<<<256, 256, 0, stream>>>(avg, iW, ib, cp, cW, cb, hbuf + 2048, cctx);
  k_pre<<<1024, 256, 0, stream>>>(lab, emb, wih, bih, ewW, ewb, gi, embw);
  k_trans<<<dim3(64, 8), 256, 0, stream>>>(cnn, ecw, ecb, ys, xs, idt, trans);
  k_mt<<<121, 256, 0, stream>>>(awW, acw, Mt);
  k_so<<<NV, 256, 0, stream>>>(sW, oW, sb, cxb, cctx, ob, SO, CB);
  k_embwO<<<NV, 512, 0, stream>>>(embw, oW, embwO);
  k_co<<<dim3(3, NV), 256, 0, stream>>>(cxW, oW, CO);
  k_gemm_PO<<<dim3(16, 2, 8), 256, 0, stream>>>(cnn, CO, PO);
  k_tr<<<128, 256, 0, stream>>>(whh, ahW, whhT, ahWT);
  k_gq0<<<dim3(4, 8), 512, 0, stream>>>(hbuf + 2048, whh, bhh, gi, hbuf);
  k_query0<<<64, 512, 0, stream>>>(hbuf, ahW, ahb, qbuf);

  for (int t = 0; t <= NT; t++){
    k_step<<<264, 512, 0, stream>>>(dmask, Mt, trans, qbuf, acvW, acvb, PO, SO, CB, embwO,
                                    gi, whhT, bhh, ahWT, ahb, hbuf, abuf, ebuf, out, t);
  }
}